// Round 19
// baseline (203.700 us; speedup 1.0000x reference)
//
#include <hip/hip_runtime.h>
#include <hip/hip_cooperative_groups.h>
#include <math.h>

namespace cg = cooperative_groups;

// ---------------------------------------------------------------------------
// GaitGraph: standardize -> GCN(2->64)+ReLU -> GCN(64->64)+ReLU -> mean-pool
//            -> linear 64->3.   N=50000, E=800000, G=2048, H=64.
// R1..R13: CSR pull, rank-2 collapse, GEMM/agg swap, u16 CSR, atomic-free
//          radix partition (585 -> 129.5us).
// R15: LDS-broadcast 4-wide edge loop + dispatch fusion (-> 94.4us).
// R16: readlane REGRESSED. R17: pool-atomic fusion REGRESSED (write-through).
// R18: R15 phase1 + k-split phase2 + B-store (-> 91.9us).
// R19: CSR chain (pre/scanA/part/bsort) fused into ONE cooperative kernel
//      k_build with grid.sync() between phases (256 blocks x 256 thr,
//      1 block/CU co-resident). 8 -> 5 dispatches; 3 launch gaps deleted.
// ---------------------------------------------------------------------------

#define H 64
#define NB 256
#define NBLK 256

__device__ __forceinline__ float nan0(float v) {
    return isfinite(v) ? v : 0.0f;
}

// Load index i from a buffer that is either int32 or int64 (flag is64).
__device__ __forceinline__ int ld_idx(const void* p, long long i, int is64) {
    if (is64) return (int)((const long long*)p)[i];
    return ((const int*)p)[i];
}

// Cooperative CSR build: phase1 pack+hist+stats-partials, phase2 scanA
// (+stats reduce), phase3 atomic-free partition, phase4 bucket sort + prepT.
__global__ __launch_bounds__(256) void k_build(
    const float* __restrict__ x, int N, const void* ei, int E,
    const int* batch, int nB, int* __restrict__ flags,
    unsigned* __restrict__ packed, int* __restrict__ histM,
    int* __restrict__ bsum, float4* __restrict__ stats_part,
    float* __restrict__ stats, unsigned* __restrict__ binned,
    unsigned short* __restrict__ csr16, int* __restrict__ counts,
    int* __restrict__ offsets, float2* __restrict__ T) {
    cg::grid_group grid = cg::this_grid();
    int blk = blockIdx.x;   // 0..255
    int tid = threadIdx.x;  // 0..255
    __shared__ int sh_a[NB], sh_b[NB], sh_c[NB];

    int eBeg = (int)((long long)blk * E / NBLK);
    int eEnd = (int)((long long)(blk + 1) * E / NBLK);

    // ---- Phase 1: stats partials + batch detect + edge pack + histogram ---
    {
        if (blk == 0) {
            __shared__ int nz_b;
            if (tid == 0) nz_b = 0;
            __syncthreads();
            long long pb = 1 + 2 * ((long long)tid * ((nB - 2) / 2) / 256);
            if (pb < nB && batch[pb] != 0) nz_b = 1;
            __syncthreads();
            if (tid == 0) flags[1] = (nz_b == 0);
        }
        float s0 = 0, s1 = 0, q0 = 0, q1 = 0;
        int gtid = blk * 256 + tid;
        for (int n = gtid; n < N; n += 256 * 256) {
            float2 v = reinterpret_cast<const float2*>(x)[n];
            float a = nan0(v.x), b = nan0(v.y);
            s0 += a; s1 += b; q0 += a * a; q1 += b * b;
        }
        for (int m = 32; m >= 1; m >>= 1) {
            s0 += __shfl_down(s0, m);
            s1 += __shfl_down(s1, m);
            q0 += __shfl_down(q0, m);
            q1 += __shfl_down(q1, m);
        }
        __shared__ float red[4][4];
        int w = tid >> 6, lane = tid & 63;
        if (lane == 0) { red[w][0] = s0; red[w][1] = s1; red[w][2] = q0; red[w][3] = q1; }
        // histogram init + local is64 detect
        __shared__ int nz_e;
        if (tid == 0) nz_e = 0;
        sh_a[tid] = 0;
        __syncthreads();
        if (tid == 0) {
            float t0 = 0, t1 = 0, t2 = 0, t3 = 0;
            for (int i = 0; i < 4; i++) {
                t0 += red[i][0]; t1 += red[i][1]; t2 += red[i][2]; t3 += red[i][3];
            }
            stats_part[blk] = make_float4(t0, t1, t2, t3);
        }
        if (tid < 64) {
            int span = eEnd - eBeg;
            long long p = 2LL * eBeg + 1 +
                          2 * ((long long)tid * (span > 1 ? span - 1 : 0) / 64);
            if (((const int*)ei)[p] != 0) nz_e = 1;
        }
        __syncthreads();
        int is64 = (nz_e == 0);
        for (int e = eBeg + tid; e < eEnd; e += 256) {
            unsigned s = (unsigned)ld_idx(ei, e, is64);
            unsigned d = (unsigned)ld_idx(ei, (long long)E + e, is64);
            packed[e] = (d << 16) | s;
            atomicAdd(&sh_a[d >> 8], 1);
        }
        __syncthreads();
        histM[tid * NBLK + blk] = sh_a[tid];
    }
    grid.sync();

    // ---- Phase 2: per-bucket scan of histM; bucket totals; stats reduce ---
    {
        int f = blk * NBLK + tid;
        int v = histM[f];
        sh_a[tid] = v;
        __syncthreads();
        for (int off = 1; off < NBLK; off <<= 1) {
            int t = (tid >= off) ? sh_a[tid - off] : 0;
            __syncthreads();
            sh_a[tid] += t;
            __syncthreads();
        }
        histM[f] = sh_a[tid] - v;
        if (tid == NBLK - 1) bsum[blk] = sh_a[NBLK - 1];
        if (blk == 0) {
            __shared__ float4 sred[256];
            sred[tid] = stats_part[tid];
            __syncthreads();
            for (int off = 128; off >= 1; off >>= 1) {
                if (tid < off) {
                    sred[tid].x += sred[tid + off].x;
                    sred[tid].y += sred[tid + off].y;
                    sred[tid].z += sred[tid + off].z;
                    sred[tid].w += sred[tid + off].w;
                }
                __syncthreads();
            }
            if (tid == 0) *reinterpret_cast<float4*>(stats) = sred[0];
        }
    }
    grid.sync();

    // ---- Phase 3: atomic-free partition (LDS cursors) ----
    {
        int v = bsum[tid];
        sh_a[tid] = v;
        __syncthreads();
        for (int off = 1; off < NB; off <<= 1) {
            int t = (tid >= off) ? sh_a[tid - off] : 0;
            __syncthreads();
            sh_a[tid] += t;
            __syncthreads();
        }
        sh_b[tid] = (sh_a[tid] - v) + histM[tid * NBLK + blk];
        __syncthreads();
        for (int e = eBeg + tid; e < eEnd; e += 256) {
            unsigned p = packed[e];
            int pos = atomicAdd(&sh_b[p >> 24], 1);  // LDS atomic
            binned[pos] = p;
        }
    }
    grid.sync();

    // ---- Phase 4: per-bucket counting sort + prepT ----
    {
        int v = bsum[tid];
        sh_a[tid] = v;
        __syncthreads();
        for (int off = 1; off < NB; off <<= 1) {
            int t = (tid >= off) ? sh_a[tid - off] : 0;
            __syncthreads();
            sh_a[tid] += t;
            __syncthreads();
        }
        __shared__ int sbeg, send;
        if (tid == blk) { sbeg = sh_a[tid] - v; send = sh_a[tid]; }
        __syncthreads();
        int beg = sbeg, end = send;
        sh_b[tid] = 0;  // hist
        __syncthreads();
        for (int i = beg + tid; i < end; i += 256)
            atomicAdd(&sh_b[(binned[i] >> 16) & 0xff], 1);
        __syncthreads();
        int hv = sh_b[tid];
        sh_c[tid] = hv;
        __syncthreads();
        for (int off = 1; off < NB; off <<= 1) {
            int t = (tid >= off) ? sh_c[tid - off] : 0;
            __syncthreads();
            sh_c[tid] += t;
            __syncthreads();
        }
        int ex = sh_c[tid] - hv;
        sh_a[tid] = ex;  // cur (bsum scan done with sh_a)
        int n = blk * NB + tid;
        if (n < N) {
            counts[n] = hv;
            offsets[n] = beg + ex;
            float sum0 = stats[0], sum1 = stats[1], q0 = stats[2], q1 = stats[3];
            float mu0 = sum0 / N, mu1 = sum1 / N;
            float v0 = fmaxf((q0 - sum0 * sum0 / N) / (N - 1), 0.0f);
            float v1 = fmaxf((q1 - sum1 * sum1 / N) / (N - 1), 0.0f);
            float r0 = 1.0f / (sqrtf(v0) + 1e-6f);
            float r1 = 1.0f / (sqrtf(v1) + 1e-6f);
            float di = rsqrtf((float)(hv + 1));
            float2 xv = reinterpret_cast<const float2*>(x)[n];
            T[n] = make_float2(di * (nan0(xv.x) - mu0) * r0,
                               di * (nan0(xv.y) - mu1) * r1);
        }
        if (n == N) offsets[N] = E;
        __syncthreads();
        for (int i = beg + tid; i < end; i += 256) {
            unsigned p = binned[i];
            int t = atomicAdd(&sh_a[(p >> 16) & 0xff], 1);
            csr16[beg + t] = (unsigned short)(p & 0xffffu);
        }
    }
}

// Layer-1 aggregation on pre-scaled T: 8 lanes per node + shfl_xor reduce.
// Emits Q[n] = (S0*di, S1*di, di, 0).
__global__ void k_aggQ(const unsigned short* __restrict__ csr16,
                       const int* __restrict__ offsets,
                       const float2* __restrict__ T,
                       const int* __restrict__ counts,
                       float4* __restrict__ Q, int N) {
    int t = blockIdx.x * blockDim.x + threadIdx.x;
    int n = t >> 3, sub = t & 7;
    if (n >= N) return;
    int beg = offsets[n], end = offsets[n + 1];
    float s0 = 0.0f, s1 = 0.0f;
    for (int k = beg + sub; k < end; k += 8) {
        float2 ts = T[csr16[k]];
        s0 += ts.x; s1 += ts.y;
    }
    s0 += __shfl_xor(s0, 1); s1 += __shfl_xor(s1, 1);
    s0 += __shfl_xor(s0, 2); s1 += __shfl_xor(s1, 2);
    s0 += __shfl_xor(s0, 4); s1 += __shfl_xor(s1, 4);
    if (sub == 0) {
        float di = rsqrtf((float)(counts[n] + 1));
        float2 tn = T[n];
        s0 += tn.x; s1 += tn.y;
        Q[n] = make_float4(s0 * di * di, s1 * di * di, di, 0.0f);
    }
}

// Fused layer-2 aggregation + GEMM + bias + relu (R18 form).
__global__ __launch_bounds__(512, 6) void k_gathgemm(
    const unsigned short* __restrict__ csr16, const int* __restrict__ offsets,
    const float4* __restrict__ Q, const float* __restrict__ W1,
    const float* __restrict__ b1, const float* __restrict__ W2,
    const float* __restrict__ b2, float* __restrict__ Bout, int N) {
    __shared__ float At[64][68];        // At[j][r] = aggY[r][j]
    __shared__ float Ws[64][64];
    __shared__ float bs[64];
    __shared__ float4 chunkW[8][2][64]; // per-wave dbuf Q entries (16KB)
    __shared__ float4 qrow[8][8];
    __shared__ int    rend[8][8];
    int tid = threadIdx.x;
    for (int i = tid; i < 64 * 64; i += 512) Ws[i >> 6][i & 63] = W2[i];
    if (tid < 64) bs[tid] = b2[tid];
    int rbase = blockIdx.x * 64;
    int wid = tid >> 6, j = tid & 63;
    float w10 = W1[j], w11 = W1[H + j], bb = b1[j];

    int r0 = min(rbase + wid * 8, N);
    int r1 = min(r0 + 8, N);
    if (r0 < r1) {
        if (j < 8 && r0 + j < r1) {
            qrow[wid][j] = Q[r0 + j];
            rend[wid][j] = offsets[r0 + j + 1];
        }
        int eBeg = offsets[r0], eEnd = offsets[r1];
        int row = 0;
        float4 qd = qrow[wid][0];
        int rowEnd = rend[wid][0];
        float di = qd.z;
        float acc = fmaxf(qd.x * w10 + qd.y * w11 + qd.z * bb, 0.0f);  // self
        if (eBeg + j < eEnd) chunkW[wid][0][j] = Q[csr16[eBeg + j]];
        int buf = 0;
        for (int base = eBeg; base < eEnd; base += 64) {
            int nbase = base + 64;
            bool hasNext = nbase < eEnd;   // wave-uniform
            float4 qn;
            if (hasNext && nbase + j < eEnd) qn = Q[csr16[nbase + j]];
            int cnt = min(64, eEnd - base);
            int k = 0;
            for (; k + 4 <= cnt; k += 4) {
                float4 q0 = chunkW[wid][buf][k + 0];
                float4 q1 = chunkW[wid][buf][k + 1];
                float4 q2 = chunkW[wid][buf][k + 2];
                float4 q3 = chunkW[wid][buf][k + 3];
                float t0 = fmaxf(q0.x * w10 + q0.y * w11 + q0.z * bb, 0.0f);
                float t1 = fmaxf(q1.x * w10 + q1.y * w11 + q1.z * bb, 0.0f);
                float t2 = fmaxf(q2.x * w10 + q2.y * w11 + q2.z * bb, 0.0f);
                float t3 = fmaxf(q3.x * w10 + q3.y * w11 + q3.z * bb, 0.0f);
                int e0 = base + k;
#pragma unroll
                for (int i = 0; i < 4; i++) {
                    while (e0 + i >= rowEnd) {   // row(s) complete (LDS only)
                        At[j][(r0 - rbase) + row] = di * acc;
                        row++;
                        rowEnd = rend[wid][row];
                        qd = qrow[wid][row];
                        di = qd.z;
                        acc = fmaxf(qd.x * w10 + qd.y * w11 + qd.z * bb, 0.0f);
                    }
                    acc += (i == 0) ? t0 : (i == 1) ? t1 : (i == 2) ? t2 : t3;
                }
            }
            for (; k < cnt; k++) {
                float4 q = chunkW[wid][buf][k];
                float tt = fmaxf(q.x * w10 + q.y * w11 + q.z * bb, 0.0f);
                int ecur = base + k;
                while (ecur >= rowEnd) {
                    At[j][(r0 - rbase) + row] = di * acc;
                    row++;
                    rowEnd = rend[wid][row];
                    qd = qrow[wid][row];
                    di = qd.z;
                    acc = fmaxf(qd.x * w10 + qd.y * w11 + qd.z * bb, 0.0f);
                }
                acc += tt;
            }
            if (hasNext) {
                if (nbase + j < eEnd) chunkW[wid][buf ^ 1][j] = qn;
                buf ^= 1;
            }
        }
        while (true) {
            At[j][(r0 - rbase) + row] = di * acc;
            row++;
            if (r0 + row >= r1) break;
            qd = qrow[wid][row];
            di = qd.z;
            acc = fmaxf(qd.x * w10 + qd.y * w11 + qd.z * bb, 0.0f);
        }
    }
    __syncthreads();
    // Phase 2: k-split. kh = tid>>8 does k in [kh*32, kh*32+32); 4x4/thread.
    int kh = tid >> 8;
    int idx = tid & 255;
    int rg = (idx >> 4) * 4;
    int cg = (idx & 15) * 4;
    float a4[4][4] = {{0.0f}};
#pragma unroll 8
    for (int k = kh * 32; k < kh * 32 + 32; k++) {
        float4 a = *reinterpret_cast<const float4*>(&At[k][rg]);
        float4 b = *reinterpret_cast<const float4*>(&Ws[k][cg]);
        a4[0][0] += a.x * b.x; a4[0][1] += a.x * b.y;
        a4[0][2] += a.x * b.z; a4[0][3] += a.x * b.w;
        a4[1][0] += a.y * b.x; a4[1][1] += a.y * b.y;
        a4[1][2] += a.y * b.z; a4[1][3] += a.y * b.w;
        a4[2][0] += a.z * b.x; a4[2][1] += a.z * b.y;
        a4[2][2] += a.z * b.z; a4[2][3] += a.z * b.w;
        a4[3][0] += a.w * b.x; a4[3][1] += a.w * b.y;
        a4[3][2] += a.w * b.z; a4[3][3] += a.w * b.w;
    }
    __syncthreads();  // chunkW free; reuse as combine buffer
    float* comb = reinterpret_cast<float*>(chunkW);  // 4096 floats
    if (kh == 1) {
#pragma unroll
        for (int i = 0; i < 16; i++)
            comb[i * 256 + idx] = a4[i >> 2][i & 3];
    }
    __syncthreads();
    if (kh == 0) {
#pragma unroll
        for (int i = 0; i < 16; i++)
            a4[i >> 2][i & 3] += comb[i * 256 + idx];
#pragma unroll
        for (int i2 = 0; i2 < 4; i2++) {
            int r = rbase + rg + i2;
            if (r < N) {
                *reinterpret_cast<float4*>(&Bout[(size_t)r * H + cg]) =
                    make_float4(fmaxf(a4[i2][0] + bs[cg + 0], 0.0f),
                                fmaxf(a4[i2][1] + bs[cg + 1], 0.0f),
                                fmaxf(a4[i2][2] + bs[cg + 2], 0.0f),
                                fmaxf(a4[i2][3] + bs[cg + 3], 0.0f));
            }
        }
    }
}

// Mean-pool per graph (sorted batch; inline binary search) + 64x3 classify.
__global__ __launch_bounds__(256) void k_poolcls(
    const float* __restrict__ B, const void* batch,
    const float* __restrict__ Wc, const float* __restrict__ bc,
    float* __restrict__ out, int N, int G, const int* __restrict__ flags) {
    int t = blockIdx.x * blockDim.x + threadIdx.x;
    int g = t >> 6, j = t & 63;
    if (g >= G) return;
    int is64 = flags[1];
    int beg, end;
    {
        int lo = 0, hi = N;
        while (lo < hi) {
            int mid = (lo + hi) >> 1;
            if (ld_idx(batch, mid, is64) < g) lo = mid + 1; else hi = mid;
        }
        beg = lo;
    }
    {
        int lo = beg, hi = N;
        while (lo < hi) {
            int mid = (lo + hi) >> 1;
            if (ld_idx(batch, mid, is64) < g + 1) lo = mid + 1; else hi = mid;
        }
        end = lo;
    }
    float a0 = 0, a1 = 0, a2 = 0, a3 = 0;
    int n = beg;
    for (; n + 4 <= end; n += 4) {
        a0 += B[(size_t)(n + 0) * H + j];
        a1 += B[(size_t)(n + 1) * H + j];
        a2 += B[(size_t)(n + 2) * H + j];
        a3 += B[(size_t)(n + 3) * H + j];
    }
    for (; n < end; n++) a0 += B[(size_t)n * H + j];
    float acc = (a0 + a1) + (a2 + a3);
    float p = acc / (float)max(end - beg, 1);
#pragma unroll
    for (int c = 0; c < 3; c++) {
        float v = p * Wc[j * 3 + c];
        for (int m = 32; m >= 1; m >>= 1) v += __shfl_xor(v, m);
        if (j == 0) out[g * 3 + c] = v + bc[c];
    }
}

extern "C" void kernel_launch(void* const* d_in, const int* in_sizes, int n_in,
                              void* d_out, int out_size, void* d_ws,
                              size_t ws_size, hipStream_t stream) {
    const float* x  = (const float*)d_in[0];
    const float* W1 = (const float*)d_in[1];
    const float* b1 = (const float*)d_in[2];
    const float* W2 = (const float*)d_in[3];
    const float* b2 = (const float*)d_in[4];
    const float* Wc = (const float*)d_in[5];
    const float* bc = (const float*)d_in[6];
    const void*  ei = d_in[7];
    const void*  batch = d_in[8];

    int N = in_sizes[0] / 2;
    int E = in_sizes[7] / 2;
    int G = out_size / 3;
    int nBatch = in_sizes[8];

    // Workspace layout (descending alignment).
    float4* Q       = (float4*)d_ws;                       // [N]
    float4* stats_part = Q + N;                            // [256]
    float*  B       = (float*)(stats_part + 256);          // [N,64]
    float2* T       = (float2*)(B + (size_t)N * H);        // [N]
    unsigned* packed = (unsigned*)(T + N);                 // [E]
    unsigned* binned = packed + E;                         // [E]
    unsigned short* csr16 = (unsigned short*)(binned + E); // [E]
    int*    histM   = (int*)(csr16 + ((E + 1) & ~1));      // [NB*NBLK]
    int*    counts  = histM + NB * NBLK;                   // [N]
    int*    offsets = counts + N;                          // [N+1]
    int*    bsum    = offsets + N + 1;                     // [NB]
    float*  stats   = (float*)(bsum + NB);                 // [8]
    int*    flags   = (int*)(stats + 8);                   // [2]

    float* out = (float*)d_out;

    // 1) cooperative CSR build (pack+hist / scan / partition / sort+prepT)
    {
        void* args[] = {(void*)&x, (void*)&N, (void*)&ei, (void*)&E,
                        (void*)&batch, (void*)&nBatch, (void*)&flags,
                        (void*)&packed, (void*)&histM, (void*)&bsum,
                        (void*)&stats_part, (void*)&stats, (void*)&binned,
                        (void*)&csr16, (void*)&counts, (void*)&offsets,
                        (void*)&T};
        hipLaunchCooperativeKernel((void*)k_build, dim3(NBLK), dim3(256),
                                   args, 0, stream);
    }
    // 2) layer-1 rank-2 aggregation -> Q (8 lanes/node)
    k_aggQ<<<(N * 8 + 255) / 256, 256, 0, stream>>>(csr16, offsets, T, counts,
                                                    Q, N);
    // 3) fused layer-2 aggregation + GEMM (k-split phase 2)
    k_gathgemm<<<(N + 63) / 64, 512, 0, stream>>>(csr16, offsets, Q, W1, b1,
                                                  W2, b2, B, N);
    // 4) pool + classify
    k_poolcls<<<(G * H + 255) / 256, 256, 0, stream>>>(B, batch, Wc, bc, out,
                                                       N, G, flags);
}

// Round 22
// 91.805 us; speedup vs baseline: 2.2188x; 2.2188x over previous
//
#include <hip/hip_runtime.h>
#include <math.h>

// ---------------------------------------------------------------------------
// GaitGraph: standardize -> GCN(2->64)+ReLU -> GCN(64->64)+ReLU -> mean-pool
//            -> linear 64->3.   N=50000, E=800000, G=2048, H=64.
// R1..R13: CSR pull, rank-2 collapse, GEMM/agg swap, u16 CSR, atomic-free
//          radix partition (585 -> 129.5us).
// R15: LDS-broadcast 4-wide edge loop + dispatch fusion (-> 94.4us).
// R16: readlane REGRESSED. R17: pool-atomic fusion REGRESSED (write-through).
// R18: R15 phase1 + k-split phase2 + B-store (-> 91.9us). BEST.
// R19: cooperative grid-sync CSR fusion REGRESSED (113us k_build). REVERTED.
// R20-R22: pure revert to R18 (R20/R21 benches died to container failures).
// ---------------------------------------------------------------------------

#define H 64
#define NB 256
#define NBLK 256

__device__ __forceinline__ float nan0(float v) {
    return isfinite(v) ? v : 0.0f;
}

// Load index i from a buffer that is either int32 or int64 (flag is64).
__device__ __forceinline__ int ld_idx(const void* p, long long i, int is64) {
    if (is64) return (int)((const long long*)p)[i];
    return ((const int*)p)[i];
}

// Fused: blocks [0,128) = feature stats partials (+ batch int64 detect in
// block 0); blocks [128,384) = edge pack + per-block bucket histogram with
// LOCAL int64 detection (odd int32 words of own chunk all zero => int64).
__global__ __launch_bounds__(256) void k_pre(
    const float* __restrict__ x, int N, float4* __restrict__ stats_part,
    const void* ei, int E, const int* batch, int nB, int* flags,
    unsigned* __restrict__ packed, int* __restrict__ histM) {
    if (blockIdx.x < 128) {
        if (blockIdx.x == 0) {
            __shared__ int nz_b;
            if (threadIdx.x == 0) nz_b = 0;
            __syncthreads();
            long long pb = 1 + 2 * ((long long)threadIdx.x * ((nB - 2) / 2) / 256);
            if (pb < nB && batch[pb] != 0) nz_b = 1;
            __syncthreads();
            if (threadIdx.x == 0) flags[1] = (nz_b == 0);
        }
        float s0 = 0, s1 = 0, q0 = 0, q1 = 0;
        int tid = blockIdx.x * blockDim.x + threadIdx.x;
        int stride = 128 * blockDim.x;
        for (int n = tid; n < N; n += stride) {
            float2 v = reinterpret_cast<const float2*>(x)[n];
            float a = nan0(v.x), b = nan0(v.y);
            s0 += a; s1 += b; q0 += a * a; q1 += b * b;
        }
        for (int m = 32; m >= 1; m >>= 1) {
            s0 += __shfl_down(s0, m);
            s1 += __shfl_down(s1, m);
            q0 += __shfl_down(q0, m);
            q1 += __shfl_down(q1, m);
        }
        __shared__ float red[4][4];
        int w = threadIdx.x >> 6, lane = threadIdx.x & 63;
        if (lane == 0) { red[w][0] = s0; red[w][1] = s1; red[w][2] = q0; red[w][3] = q1; }
        __syncthreads();
        if (threadIdx.x == 0) {
            float t0 = 0, t1 = 0, t2 = 0, t3 = 0;
            for (int i = 0; i < 4; i++) {
                t0 += red[i][0]; t1 += red[i][1]; t2 += red[i][2]; t3 += red[i][3];
            }
            stats_part[blockIdx.x] = make_float4(t0, t1, t2, t3);
        }
    } else {
        int blk = blockIdx.x - 128;
        int beg = (int)((long long)blk * E / NBLK);
        int end = (int)((long long)(blk + 1) * E / NBLK);
        __shared__ int hist[NB];
        __shared__ int nz_e;
        if (threadIdx.x == 0) nz_e = 0;
        for (int i = threadIdx.x; i < NB; i += 256) hist[i] = 0;
        __syncthreads();
        if (threadIdx.x < 64) {
            int span = end - beg;
            long long p = 2LL * beg + 1 +
                          2 * ((long long)threadIdx.x * (span > 1 ? span - 1 : 0) / 64);
            if (((const int*)ei)[p] != 0) nz_e = 1;
        }
        __syncthreads();
        int is64 = (nz_e == 0);
        for (int e = beg + threadIdx.x; e < end; e += 256) {
            unsigned s = (unsigned)ld_idx(ei, e, is64);
            unsigned d = (unsigned)ld_idx(ei, (long long)E + e, is64);
            packed[e] = (d << 16) | s;
            atomicAdd(&hist[d >> 8], 1);
        }
        __syncthreads();
        for (int i = threadIdx.x; i < NB; i += 256)
            histM[i * NBLK + blk] = hist[i];
    }
}

// scanA: block b = bucket b; exclusive scan of histM[b*NBLK..+NBLK) in place;
// bucket total -> bsum[b]. Block 0 additionally reduces stats partials.
__global__ __launch_bounds__(256) void k_scanA(int* __restrict__ histM,
                                               int* __restrict__ bsum,
                                               const float4* __restrict__ stats_part,
                                               float* __restrict__ stats) {
    __shared__ int tmp[NBLK];
    int f = blockIdx.x * NBLK + threadIdx.x;
    int v = histM[f];
    tmp[threadIdx.x] = v;
    if (blockIdx.x == 0) {
        __shared__ float4 sred[128];
        if (threadIdx.x < 128) sred[threadIdx.x] = stats_part[threadIdx.x];
        __syncthreads();
        for (int off = 64; off >= 1; off >>= 1) {
            if (threadIdx.x < off) {
                sred[threadIdx.x].x += sred[threadIdx.x + off].x;
                sred[threadIdx.x].y += sred[threadIdx.x + off].y;
                sred[threadIdx.x].z += sred[threadIdx.x + off].z;
                sred[threadIdx.x].w += sred[threadIdx.x + off].w;
            }
            __syncthreads();
        }
        if (threadIdx.x == 0) *reinterpret_cast<float4*>(stats) = sred[0];
    } else {
        __syncthreads();
    }
    __syncthreads();
    for (int off = 1; off < NBLK; off <<= 1) {
        int t = (threadIdx.x >= off) ? tmp[threadIdx.x - off] : 0;
        __syncthreads();
        tmp[threadIdx.x] += t;
        __syncthreads();
    }
    histM[f] = tmp[threadIdx.x] - v;
    if (threadIdx.x == NBLK - 1) bsum[blockIdx.x] = tmp[NBLK - 1];
}

// Atomic-free partition. Each block locally scans bsum for bucket bases,
// adds its per-bucket within-bucket prefix (histM), keeps cursors in LDS.
__global__ __launch_bounds__(256) void k_part(const unsigned* __restrict__ packed,
                                              const int* __restrict__ histM,
                                              const int* __restrict__ bsum,
                                              unsigned* __restrict__ binned,
                                              int E) {
    __shared__ int sb[NB];
    __shared__ int cur[NB];
    int blk = blockIdx.x;
    int v = bsum[threadIdx.x];
    sb[threadIdx.x] = v;
    __syncthreads();
    for (int off = 1; off < NB; off <<= 1) {
        int t = (threadIdx.x >= off) ? sb[threadIdx.x - off] : 0;
        __syncthreads();
        sb[threadIdx.x] += t;
        __syncthreads();
    }
    cur[threadIdx.x] = (sb[threadIdx.x] - v) + histM[threadIdx.x * NBLK + blk];
    __syncthreads();
    int beg = (int)((long long)blk * E / NBLK);
    int end = (int)((long long)(blk + 1) * E / NBLK);
    for (int e = beg + threadIdx.x; e < end; e += 256) {
        unsigned p = packed[e];
        int pos = atomicAdd(&cur[p >> 24], 1);  // LDS atomic
        binned[pos] = p;
    }
}

// Per-bucket counting sort + prepT. Block b locally scans bsum for its base.
// Emits csr16, counts, offsets (+ sentinel), T.
__global__ __launch_bounds__(256) void k_bsort(
    const unsigned* __restrict__ binned, const int* __restrict__ bsum,
    unsigned short* __restrict__ csr16, int* __restrict__ counts,
    int* __restrict__ offsets, const float* __restrict__ x,
    const float* __restrict__ stats, float2* __restrict__ T, int N, int E) {
    __shared__ int hist[NB], tmp[NB], cur[NB];
    __shared__ int sbeg, send;
    int b = blockIdx.x;
    {
        int v = bsum[threadIdx.x];
        tmp[threadIdx.x] = v;
        __syncthreads();
        for (int off = 1; off < NB; off <<= 1) {
            int t = (threadIdx.x >= off) ? tmp[threadIdx.x - off] : 0;
            __syncthreads();
            tmp[threadIdx.x] += t;
            __syncthreads();
        }
        if (threadIdx.x == b) { sbeg = tmp[threadIdx.x] - v; send = tmp[threadIdx.x]; }
    }
    __syncthreads();
    int beg = sbeg, end = send;
    hist[threadIdx.x] = 0;
    __syncthreads();
    for (int i = beg + threadIdx.x; i < end; i += 256)
        atomicAdd(&hist[(binned[i] >> 16) & 0xff], 1);
    __syncthreads();
    int v = hist[threadIdx.x];
    tmp[threadIdx.x] = v;
    __syncthreads();
    for (int off = 1; off < NB; off <<= 1) {
        int t = (threadIdx.x >= off) ? tmp[threadIdx.x - off] : 0;
        __syncthreads();
        tmp[threadIdx.x] += t;
        __syncthreads();
    }
    int ex = tmp[threadIdx.x] - v;
    cur[threadIdx.x] = ex;
    int n = b * NB + threadIdx.x;
    if (n < N) {
        counts[n] = v;
        offsets[n] = beg + ex;
        float sum0 = stats[0], sum1 = stats[1], q0 = stats[2], q1 = stats[3];
        float mu0 = sum0 / N, mu1 = sum1 / N;
        float v0 = fmaxf((q0 - sum0 * sum0 / N) / (N - 1), 0.0f);
        float v1 = fmaxf((q1 - sum1 * sum1 / N) / (N - 1), 0.0f);
        float r0 = 1.0f / (sqrtf(v0) + 1e-6f);
        float r1 = 1.0f / (sqrtf(v1) + 1e-6f);
        float di = rsqrtf((float)(v + 1));
        float2 xv = reinterpret_cast<const float2*>(x)[n];
        T[n] = make_float2(di * (nan0(xv.x) - mu0) * r0,
                           di * (nan0(xv.y) - mu1) * r1);
    }
    if (n == N) offsets[N] = E;
    __syncthreads();
    for (int i = beg + threadIdx.x; i < end; i += 256) {
        unsigned p = binned[i];
        int t = atomicAdd(&cur[(p >> 16) & 0xff], 1);
        csr16[beg + t] = (unsigned short)(p & 0xffffu);
    }
}

// Layer-1 aggregation on pre-scaled T: 8 lanes per node + shfl_xor reduce.
// Emits Q[n] = (S0*di, S1*di, di, 0).
__global__ void k_aggQ(const unsigned short* __restrict__ csr16,
                       const int* __restrict__ offsets,
                       const float2* __restrict__ T,
                       const int* __restrict__ counts,
                       float4* __restrict__ Q, int N) {
    int t = blockIdx.x * blockDim.x + threadIdx.x;
    int n = t >> 3, sub = t & 7;
    if (n >= N) return;
    int beg = offsets[n], end = offsets[n + 1];
    float s0 = 0.0f, s1 = 0.0f;
    for (int k = beg + sub; k < end; k += 8) {
        float2 ts = T[csr16[k]];
        s0 += ts.x; s1 += ts.y;
    }
    s0 += __shfl_xor(s0, 1); s1 += __shfl_xor(s1, 1);
    s0 += __shfl_xor(s0, 2); s1 += __shfl_xor(s1, 2);
    s0 += __shfl_xor(s0, 4); s1 += __shfl_xor(s1, 4);
    if (sub == 0) {
        float di = rsqrtf((float)(counts[n] + 1));
        float2 tn = T[n];
        s0 += tn.x; s1 += tn.y;
        Q[n] = make_float4(s0 * di * di, s1 * di * di, di, 0.0f);
    }
}

// Fused layer-2 aggregation + GEMM + bias + relu.
// 512 threads = 8 waves; wave w owns rows [w*8, w*8+8). Phase 1 (R15 form):
// chunked global gather -> LDS dbuf -> per-edge broadcast ds_read, 4-wide.
// Phase 2: k-split 4x4 register tile (2 k-halves x 256 threads) + LDS
// combine; kh==0 writes B with bias+relu (coalesced float4).
__global__ __launch_bounds__(512, 6) void k_gathgemm(
    const unsigned short* __restrict__ csr16, const int* __restrict__ offsets,
    const float4* __restrict__ Q, const float* __restrict__ W1,
    const float* __restrict__ b1, const float* __restrict__ W2,
    const float* __restrict__ b2, float* __restrict__ Bout, int N) {
    __shared__ float At[64][68];        // At[j][r] = aggY[r][j]
    __shared__ float Ws[64][64];
    __shared__ float bs[64];
    __shared__ float4 chunkW[8][2][64]; // per-wave dbuf Q entries (16KB)
    __shared__ float4 qrow[8][8];
    __shared__ int    rend[8][8];
    int tid = threadIdx.x;
    for (int i = tid; i < 64 * 64; i += 512) Ws[i >> 6][i & 63] = W2[i];
    if (tid < 64) bs[tid] = b2[tid];
    int rbase = blockIdx.x * 64;
    int wid = tid >> 6, j = tid & 63;
    float w10 = W1[j], w11 = W1[H + j], bb = b1[j];

    int r0 = min(rbase + wid * 8, N);
    int r1 = min(r0 + 8, N);
    if (r0 < r1) {
        if (j < 8 && r0 + j < r1) {
            qrow[wid][j] = Q[r0 + j];
            rend[wid][j] = offsets[r0 + j + 1];
        }
        int eBeg = offsets[r0], eEnd = offsets[r1];
        int row = 0;
        float4 qd = qrow[wid][0];
        int rowEnd = rend[wid][0];
        float di = qd.z;
        float acc = fmaxf(qd.x * w10 + qd.y * w11 + qd.z * bb, 0.0f);  // self
        if (eBeg + j < eEnd) chunkW[wid][0][j] = Q[csr16[eBeg + j]];
        int buf = 0;
        for (int base = eBeg; base < eEnd; base += 64) {
            int nbase = base + 64;
            bool hasNext = nbase < eEnd;   // wave-uniform
            float4 qn;
            if (hasNext && nbase + j < eEnd) qn = Q[csr16[nbase + j]];
            int cnt = min(64, eEnd - base);
            int k = 0;
            for (; k + 4 <= cnt; k += 4) {
                float4 q0 = chunkW[wid][buf][k + 0];
                float4 q1 = chunkW[wid][buf][k + 1];
                float4 q2 = chunkW[wid][buf][k + 2];
                float4 q3 = chunkW[wid][buf][k + 3];
                float t0 = fmaxf(q0.x * w10 + q0.y * w11 + q0.z * bb, 0.0f);
                float t1 = fmaxf(q1.x * w10 + q1.y * w11 + q1.z * bb, 0.0f);
                float t2 = fmaxf(q2.x * w10 + q2.y * w11 + q2.z * bb, 0.0f);
                float t3 = fmaxf(q3.x * w10 + q3.y * w11 + q3.z * bb, 0.0f);
                int e0 = base + k;
#pragma unroll
                for (int i = 0; i < 4; i++) {
                    while (e0 + i >= rowEnd) {   // row(s) complete (LDS only)
                        At[j][(r0 - rbase) + row] = di * acc;
                        row++;
                        rowEnd = rend[wid][row];
                        qd = qrow[wid][row];
                        di = qd.z;
                        acc = fmaxf(qd.x * w10 + qd.y * w11 + qd.z * bb, 0.0f);
                    }
                    acc += (i == 0) ? t0 : (i == 1) ? t1 : (i == 2) ? t2 : t3;
                }
            }
            for (; k < cnt; k++) {
                float4 q = chunkW[wid][buf][k];
                float tt = fmaxf(q.x * w10 + q.y * w11 + q.z * bb, 0.0f);
                int ecur = base + k;
                while (ecur >= rowEnd) {
                    At[j][(r0 - rbase) + row] = di * acc;
                    row++;
                    rowEnd = rend[wid][row];
                    qd = qrow[wid][row];
                    di = qd.z;
                    acc = fmaxf(qd.x * w10 + qd.y * w11 + qd.z * bb, 0.0f);
                }
                acc += tt;
            }
            if (hasNext) {
                if (nbase + j < eEnd) chunkW[wid][buf ^ 1][j] = qn;
                buf ^= 1;
            }
        }
        while (true) {
            At[j][(r0 - rbase) + row] = di * acc;
            row++;
            if (r0 + row >= r1) break;
            qd = qrow[wid][row];
            di = qd.z;
            acc = fmaxf(qd.x * w10 + qd.y * w11 + qd.z * bb, 0.0f);
        }
    }
    __syncthreads();
    // Phase 2: k-split. kh = tid>>8 does k in [kh*32, kh*32+32); 4x4/thread.
    int kh = tid >> 8;
    int idx = tid & 255;
    int rg = (idx >> 4) * 4;
    int cg = (idx & 15) * 4;
    float a4[4][4] = {{0.0f}};
#pragma unroll 8
    for (int k = kh * 32; k < kh * 32 + 32; k++) {
        float4 a = *reinterpret_cast<const float4*>(&At[k][rg]);
        float4 b = *reinterpret_cast<const float4*>(&Ws[k][cg]);
        a4[0][0] += a.x * b.x; a4[0][1] += a.x * b.y;
        a4[0][2] += a.x * b.z; a4[0][3] += a.x * b.w;
        a4[1][0] += a.y * b.x; a4[1][1] += a.y * b.y;
        a4[1][2] += a.y * b.z; a4[1][3] += a.y * b.w;
        a4[2][0] += a.z * b.x; a4[2][1] += a.z * b.y;
        a4[2][2] += a.z * b.z; a4[2][3] += a.z * b.w;
        a4[3][0] += a.w * b.x; a4[3][1] += a.w * b.y;
        a4[3][2] += a.w * b.z; a4[3][3] += a.w * b.w;
    }
    __syncthreads();  // chunkW free; reuse as combine buffer
    float* comb = reinterpret_cast<float*>(chunkW);  // 4096 floats
    if (kh == 1) {
#pragma unroll
        for (int i = 0; i < 16; i++)
            comb[i * 256 + idx] = a4[i >> 2][i & 3];
    }
    __syncthreads();
    if (kh == 0) {
#pragma unroll
        for (int i = 0; i < 16; i++)
            a4[i >> 2][i & 3] += comb[i * 256 + idx];
#pragma unroll
        for (int i2 = 0; i2 < 4; i2++) {
            int r = rbase + rg + i2;
            if (r < N) {
                *reinterpret_cast<float4*>(&Bout[(size_t)r * H + cg]) =
                    make_float4(fmaxf(a4[i2][0] + bs[cg + 0], 0.0f),
                                fmaxf(a4[i2][1] + bs[cg + 1], 0.0f),
                                fmaxf(a4[i2][2] + bs[cg + 2], 0.0f),
                                fmaxf(a4[i2][3] + bs[cg + 3], 0.0f));
            }
        }
    }
}

// Mean-pool per graph (sorted batch; inline binary search) + 64x3 classify.
__global__ __launch_bounds__(256) void k_poolcls(
    const float* __restrict__ B, const void* batch,
    const float* __restrict__ Wc, const float* __restrict__ bc,
    float* __restrict__ out, int N, int G, const int* __restrict__ flags) {
    int t = blockIdx.x * blockDim.x + threadIdx.x;
    int g = t >> 6, j = t & 63;
    if (g >= G) return;
    int is64 = flags[1];
    int beg, end;
    {
        int lo = 0, hi = N;
        while (lo < hi) {
            int mid = (lo + hi) >> 1;
            if (ld_idx(batch, mid, is64) < g) lo = mid + 1; else hi = mid;
        }
        beg = lo;
    }
    {
        int lo = beg, hi = N;
        while (lo < hi) {
            int mid = (lo + hi) >> 1;
            if (ld_idx(batch, mid, is64) < g + 1) lo = mid + 1; else hi = mid;
        }
        end = lo;
    }
    float a0 = 0, a1 = 0, a2 = 0, a3 = 0;
    int n = beg;
    for (; n + 4 <= end; n += 4) {
        a0 += B[(size_t)(n + 0) * H + j];
        a1 += B[(size_t)(n + 1) * H + j];
        a2 += B[(size_t)(n + 2) * H + j];
        a3 += B[(size_t)(n + 3) * H + j];
    }
    for (; n < end; n++) a0 += B[(size_t)n * H + j];
    float acc = (a0 + a1) + (a2 + a3);
    float p = acc / (float)max(end - beg, 1);
#pragma unroll
    for (int c = 0; c < 3; c++) {
        float v = p * Wc[j * 3 + c];
        for (int m = 32; m >= 1; m >>= 1) v += __shfl_xor(v, m);
        if (j == 0) out[g * 3 + c] = v + bc[c];
    }
}

extern "C" void kernel_launch(void* const* d_in, const int* in_sizes, int n_in,
                              void* d_out, int out_size, void* d_ws,
                              size_t ws_size, hipStream_t stream) {
    const float* x  = (const float*)d_in[0];
    const float* W1 = (const float*)d_in[1];
    const float* b1 = (const float*)d_in[2];
    const float* W2 = (const float*)d_in[3];
    const float* b2 = (const float*)d_in[4];
    const float* Wc = (const float*)d_in[5];
    const float* bc = (const float*)d_in[6];
    const void*  ei = d_in[7];
    const void*  batch = d_in[8];

    int N = in_sizes[0] / 2;
    int E = in_sizes[7] / 2;
    int G = out_size / 3;

    // Workspace layout (descending alignment).
    float4* Q       = (float4*)d_ws;                       // [N]
    float4* stats_part = Q + N;                            // [128]
    float*  B       = (float*)(stats_part + 128);          // [N,64]
    float2* T       = (float2*)(B + (size_t)N * H);        // [N]
    unsigned* packed = (unsigned*)(T + N);                 // [E]
    unsigned* binned = packed + E;                         // [E]
    unsigned short* csr16 = (unsigned short*)(binned + E); // [E]
    int*    histM   = (int*)(csr16 + ((E + 1) & ~1));      // [NB*NBLK]
    int*    counts  = histM + NB * NBLK;                   // [N]
    int*    offsets = counts + N;                          // [N+1]
    int*    bsum    = offsets + N + 1;                     // [NB]
    float*  stats   = (float*)(bsum + NB);                 // [8]
    int*    flags   = (int*)(stats + 8);                   // [2]

    float* out = (float*)d_out;

    // 1) fused stats-partials + edge pack/histogram
    k_pre<<<384, 256, 0, stream>>>(x, N, stats_part, ei, E,
                                   (const int*)batch, in_sizes[8], flags,
                                   packed, histM);
    // 2) per-bucket scan (+ stats reduce in block 0)
    k_scanA<<<NB, NBLK, 0, stream>>>(histM, bsum, stats_part, stats);
    // 3) atomic-free partition (bucket bases computed locally)
    k_part<<<NBLK, 256, 0, stream>>>(packed, histM, bsum, binned, E);
    // 4) per-bucket counting sort + prepT
    k_bsort<<<NB, NB, 0, stream>>>(binned, bsum, csr16, counts, offsets,
                                   x, stats, T, N, E);
    // 5) layer-1 rank-2 aggregation -> Q (8 lanes/node)
    k_aggQ<<<(N * 8 + 255) / 256, 256, 0, stream>>>(csr16, offsets, T, counts,
                                                    Q, N);
    // 6) fused layer-2 aggregation + GEMM (k-split phase 2)
    k_gathgemm<<<(N + 63) / 64, 512, 0, stream>>>(csr16, offsets, Q, W1, b1,
                                                  W2, b2, B, N);
    // 7) pool + classify
    k_poolcls<<<(G * H + 255) / 256, 256, 0, stream>>>(B, batch, Wc, bc, out,
                                                       N, G, flags);
}